// Round 1
// baseline (1044.481 us; speedup 1.0000x reference)
//
#include <hip/hip_runtime.h>
#include <stdint.h>
#include <stddef.h>

// QuantizedColumnParallel: y[4096,16384] = x[4096,4096] @ (wq[16384,4096]*scale)^T + bias
// Strategy: x -> f16 (rel err 2^-11), wq -> f16 (EXACT for |v|<=127), f16 MFMA fp32-accum,
// scale+bias fused in epilogue. m97-structure 128^2 tile, global_load_lds w=16,
// both-sides XOR swizzle (rule #21).

#define M_TOT 4096
#define N_TOT 16384
#define K_TOT 4096
#define BM 128
#define BN 128
#define BK 64

typedef __attribute__((ext_vector_type(8))) _Float16 f16x8;
typedef __attribute__((ext_vector_type(4))) _Float16 f16x4;
typedef __attribute__((ext_vector_type(4))) float    f32x4;

#define GLOAD_LDS16(g, l) __builtin_amdgcn_global_load_lds(                  \
    (const __attribute__((address_space(1))) void*)(g),                      \
    (__attribute__((address_space(3))) void*)(l), 16, 0, 0)

// ---------------- conversion pre-passes ----------------

__global__ __launch_bounds__(256) void cvt_x_f16(const float* __restrict__ x,
                                                 _Float16* __restrict__ o, int n4) {
  const int stride = gridDim.x * blockDim.x;
  for (int i = blockIdx.x * blockDim.x + threadIdx.x; i < n4; i += stride) {
    float4 v = ((const float4*)x)[i];
    f16x4 h = { (_Float16)v.x, (_Float16)v.y, (_Float16)v.z, (_Float16)v.w };
    ((f16x4*)o)[i] = h;
  }
}

__global__ __launch_bounds__(256) void cvt_w_f16(const int* __restrict__ w,
                                                 _Float16* __restrict__ o, int n4) {
  const int stride = gridDim.x * blockDim.x;
  for (int i = blockIdx.x * blockDim.x + threadIdx.x; i < n4; i += stride) {
    int4 v = ((const int4*)w)[i];
    f16x4 h = { (_Float16)v.x, (_Float16)v.y, (_Float16)v.z, (_Float16)v.w };
    ((f16x4*)o)[i] = h;
  }
}

// ---------------- GEMM ----------------
// DIRECT=false: A16/B16 are pre-converted f16 in workspace (global_load_lds path).
// DIRECT=true : fallback, reads fp32 x / int32 w directly, converts in regs, ds_write.

template <bool DIRECT>
__global__ __launch_bounds__(256) void gemm_qcp(
    const _Float16* __restrict__ A16, const _Float16* __restrict__ B16,
    const float* __restrict__ Xf, const int* __restrict__ Wq,
    const float* __restrict__ scale_p, const float* __restrict__ bias,
    float* __restrict__ out)
{
  __shared__ _Float16 ldsA[BM * BK];   // 16 KiB
  __shared__ _Float16 ldsB[BN * BK];   // 16 KiB

  const int tid  = threadIdx.x;
  const int lane = tid & 63;
  const int wave = tid >> 6;
  const int wr = wave >> 1;            // 0..1  (M wave row)
  const int wc = wave & 1;             // 0..1  (N wave col)

  // XCD-aware bijective swizzle: 4096 blocks, 8 XCDs, 512 contiguous wg per XCD.
  const int bid = blockIdx.x;
  const int wg  = (bid & 7) * 512 + (bid >> 3);
  const int bm  = wg & 31;             // 32 M-blocks (consecutive wg share B panel)
  const int bn  = wg >> 5;             // 128 N-blocks

  const int arow0 = bm * BM;
  const int brow0 = bn * BN;

  f32x4 acc[4][4];
#pragma unroll
  for (int m = 0; m < 4; ++m)
#pragma unroll
    for (int n = 0; n < 4; ++n)
      acc[m][n] = (f32x4){0.f, 0.f, 0.f, 0.f};

  const int srow   = tid >> 3;  // 0..31  staged row within 32-row slab
  const int schunk = tid & 7;   // 0..7   16B chunk within 64-elem row

  const int lr = lane & 15;
  const int hi = lane >> 4;

  for (int kt = 0; kt < K_TOT / BK; ++kt) {
    const size_t kbase = (size_t)kt * BK;
    __syncthreads();                     // all waves done reading previous tile

    if (!DIRECT) {
#pragma unroll
      for (int i = 0; i < 4; ++i) {
        const int row = i * 32 + srow;
        const int sc  = schunk ^ (row & 7);   // pre-swizzled global source chunk
        const _Float16* gA = A16 + (size_t)(arow0 + row) * K_TOT + kbase + sc * 8;
        const _Float16* gB = B16 + (size_t)(brow0 + row) * K_TOT + kbase + sc * 8;
        // LDS dest linear: i*2048 + tid*8 elems == row*64 + schunk*8
        GLOAD_LDS16(gA, ldsA + i * 2048 + tid * 8);
        GLOAD_LDS16(gB, ldsB + i * 2048 + tid * 8);
      }
    } else {
#pragma unroll
      for (int i = 0; i < 4; ++i) {
        const int row = i * 32 + srow;
        const int p   = schunk ^ (row & 7);   // swizzled LDS chunk position
        const float* gx = Xf + (size_t)(arow0 + row) * K_TOT + kbase + schunk * 8;
        const int*   gw = Wq + (size_t)(brow0 + row) * K_TOT + kbase + schunk * 8;
        float4 x0 = ((const float4*)gx)[0];
        float4 x1 = ((const float4*)gx)[1];
        int4   w0 = ((const int4*)gw)[0];
        int4   w1 = ((const int4*)gw)[1];
        f16x8 ha = { (_Float16)x0.x, (_Float16)x0.y, (_Float16)x0.z, (_Float16)x0.w,
                     (_Float16)x1.x, (_Float16)x1.y, (_Float16)x1.z, (_Float16)x1.w };
        f16x8 hb = { (_Float16)w0.x, (_Float16)w0.y, (_Float16)w0.z, (_Float16)w0.w,
                     (_Float16)w1.x, (_Float16)w1.y, (_Float16)w1.z, (_Float16)w1.w };
        *(f16x8*)(ldsA + row * 64 + p * 8) = ha;
        *(f16x8*)(ldsB + row * 64 + p * 8) = hb;
      }
    }
    __syncthreads();                     // drains vmcnt/lgkmcnt (compiler-inserted)

#pragma unroll
    for (int s = 0; s < 2; ++s) {        // two K=32 sub-steps of BK=64
      f16x8 af[4], bf[4];
#pragma unroll
      for (int m = 0; m < 4; ++m) {
        const int r = wr * 64 + m * 16 + lr;
        const int c = (s * 4 + hi) ^ (r & 7);     // swizzled read
        af[m] = *(const f16x8*)(ldsA + r * 64 + c * 8);
      }
#pragma unroll
      for (int n = 0; n < 4; ++n) {
        const int r = wc * 64 + n * 16 + lr;
        const int c = (s * 4 + hi) ^ (r & 7);
        bf[n] = *(const f16x8*)(ldsB + r * 64 + c * 8);
      }
#pragma unroll
      for (int m = 0; m < 4; ++m)
#pragma unroll
        for (int n = 0; n < 4; ++n)
          acc[m][n] = __builtin_amdgcn_mfma_f32_16x16x32_f16(af[m], bf[n], acc[m][n], 0, 0, 0);
    }
  }

  // Epilogue: y = acc*scale + bias. C/D layout: col=lane&15, row=(lane>>4)*4+reg.
  const float s = scale_p[0];
#pragma unroll
  for (int n = 0; n < 4; ++n) {
    const int col = brow0 + wc * 64 + n * 16 + lr;
    const float bv = bias[col];
#pragma unroll
    for (int m = 0; m < 4; ++m) {
      const int row0 = arow0 + wr * 64 + m * 16 + hi * 4;
      const f32x4 v = acc[m][n];
#pragma unroll
      for (int j = 0; j < 4; ++j)
        out[(size_t)(row0 + j) * N_TOT + col] = v[j] * s + bv;
    }
  }
}

// ---------------- launch ----------------

extern "C" void kernel_launch(void* const* d_in, const int* in_sizes, int n_in,
                              void* d_out, int out_size, void* d_ws, size_t ws_size,
                              hipStream_t stream) {
  const float* x     = (const float*)d_in[0];
  const int*   wq    = (const int*)d_in[1];
  const float* scale = (const float*)d_in[2];
  const float* bias  = (const float*)d_in[3];
  float*       out   = (float*)d_out;

  const size_t nA = (size_t)M_TOT * K_TOT;   // 16.7M
  const size_t nB = (size_t)N_TOT * K_TOT;   // 67.1M
  const size_t need = (nA + nB) * sizeof(_Float16);  // 160 MiB

  const dim3 grid(( M_TOT / BM) * (N_TOT / BN));     // 4096 blocks
  const dim3 block(256);

  if (ws_size >= need) {
    _Float16* A16 = (_Float16*)d_ws;
    _Float16* B16 = A16 + nA;
    cvt_x_f16<<<2048, 256, 0, stream>>>(x, A16, (int)(nA / 4));
    cvt_w_f16<<<2048, 256, 0, stream>>>(wq, B16, (int)(nB / 4));
    gemm_qcp<false><<<grid, block, 0, stream>>>(A16, B16, nullptr, nullptr,
                                                scale, bias, out);
  } else {
    gemm_qcp<true><<<grid, block, 0, stream>>>(nullptr, nullptr, x, wq,
                                               scale, bias, out);
  }
}

// Round 2
// 678.699 us; speedup vs baseline: 1.5389x; 1.5389x over previous
//
#include <hip/hip_runtime.h>
#include <stdint.h>
#include <stddef.h>

// QuantizedColumnParallel: y[4096,16384] = x[4096,4096] @ (wq[16384,4096]*scale)^T + bias
// R2: 256x256 8-phase pipelined GEMM (T1+T2+T3+T4+T5), f16 MFMA fp32-accum.
// K-split half-tiles: each K-tile (BK=64) = {A_k0,A_k1,B_k0,B_k1}, 256x32 f16 each,
// double-buffered => 128 KiB LDS. Counted vmcnt(6) keeps 3 half-tiles in flight.

#define M_TOT 4096
#define N_TOT 16384
#define K_TOT 4096
#define NT    64          // K_TOT / 64
#define HALF  8192        // 256 rows * 32 cols (f16 elems) per K-half region

typedef __attribute__((ext_vector_type(8))) _Float16 f16x8;
typedef __attribute__((ext_vector_type(4))) _Float16 f16x4;
typedef __attribute__((ext_vector_type(4))) float    f32x4;

#define GLOAD_LDS16(g, l) __builtin_amdgcn_global_load_lds(                  \
    (const __attribute__((address_space(1))) void*)(g),                      \
    (__attribute__((address_space(3))) void*)(l), 16, 0, 0)

// ---------------- conversion pre-passes ----------------

__global__ __launch_bounds__(256) void cvt_x_f16(const float* __restrict__ x,
                                                 _Float16* __restrict__ o, int n4) {
  const int stride = gridDim.x * blockDim.x;
  for (int i = blockIdx.x * blockDim.x + threadIdx.x; i < n4; i += stride) {
    float4 v = ((const float4*)x)[i];
    f16x4 h = { (_Float16)v.x, (_Float16)v.y, (_Float16)v.z, (_Float16)v.w };
    ((f16x4*)o)[i] = h;
  }
}

__global__ __launch_bounds__(256) void cvt_w_f16(const int* __restrict__ w,
                                                 _Float16* __restrict__ o, int n4) {
  const int stride = gridDim.x * blockDim.x;
  for (int i = blockIdx.x * blockDim.x + threadIdx.x; i < n4; i += stride) {
    int4 v = ((const int4*)w)[i];
    f16x4 h = { (_Float16)v.x, (_Float16)v.y, (_Float16)v.z, (_Float16)v.w };
    ((f16x4*)o)[i] = h;
  }
}

// ---------------- 8-phase 256^2 GEMM ----------------

// Stage one K-half region (256 rows x 32 f16 = 16 KiB): 2 x global_load_lds(16B)
// per thread. LDS dest is linear (uniform base + lane*16); the XOR swizzle is
// applied on the GLOBAL source chunk (rule #21: swizzle both sides or neither).
__device__ __forceinline__ void stage_half(const _Float16* __restrict__ g,
                                           size_t kcol, _Float16* l, int tid) {
#pragma unroll
  for (int j = 0; j < 2; ++j) {
    const int ci  = j * 512 + tid;       // 0..1023 16B-chunks
    const int row = ci >> 2;             // 0..255
    const int sc  = (ci & 3) ^ (row & 3);
    GLOAD_LDS16(g + (size_t)row * K_TOT + kcol + sc * 8, l + ci * 8);
  }
}

// Swizzled fragment read: row r, K-chunk hi (0..3) within a 256x32 region.
// 8 consecutive lanes hit 4 chunk-slots twice => worst 2-way conflict (free, m136).
__device__ __forceinline__ f16x8 frag(const _Float16* region, int r, int hi) {
  return *(const f16x8*)(region + r * 32 + ((hi ^ (r & 3)) * 8));
}

#define BAR()    __builtin_amdgcn_s_barrier()
#define LGKM0()  do { asm volatile("s_waitcnt lgkmcnt(0)" ::: "memory"); \
                      __builtin_amdgcn_sched_barrier(0); } while (0)

__global__ __launch_bounds__(512, 2) void gemm8p(
    const _Float16* __restrict__ A16, const _Float16* __restrict__ B16,
    const float* __restrict__ scale_p, const float* __restrict__ bias,
    float* __restrict__ out)
{
  // smem[buf][A=0|B=1][khalf][256*32]  = 128 KiB
  __shared__ _Float16 smem[2][2][2][HALF];

  const int tid  = threadIdx.x;
  const int lane = tid & 63;
  const int wave = tid >> 6;
  const int wr = wave >> 2;            // 0..1 (M)
  const int wc = wave & 3;             // 0..3 (N)
  const int lr = lane & 15;
  const int hi = lane >> 4;

  // XCD-aware swizzle: 1024 wg, 8 XCDs, 128 contiguous per XCD.
  // bm fast (16) => each XCD owns 8 bn panels; A (32MB) L3-resident.
  const int bid = blockIdx.x;
  const int wg  = (bid & 7) * 128 + (bid >> 3);
  const int bm  = wg & 15;
  const int bn  = wg >> 4;
  const int arow0 = bm * 256;
  const int brow0 = bn * 256;

  const _Float16* Ag = A16 + (size_t)arow0 * K_TOT;
  const _Float16* Bg = B16 + (size_t)brow0 * K_TOT;

  f32x4 acc[8][4];
#pragma unroll
  for (int m = 0; m < 8; ++m)
#pragma unroll
    for (int n = 0; n < 4; ++n)
      acc[m][n] = (f32x4){0.f, 0.f, 0.f, 0.f};

  // ---- prologue: tile0 fully + {B_k0,A_k0,B_k1} of tile1 (issue order matters!)
  stage_half(Bg, 0,  &smem[0][1][0][0], tid);   // B_k0(0)
  stage_half(Ag, 0,  &smem[0][0][0][0], tid);   // A_k0(0)
  stage_half(Bg, 32, &smem[0][1][1][0], tid);   // B_k1(0)
  stage_half(Ag, 32, &smem[0][0][1][0], tid);   // A_k1(0)
  stage_half(Bg, 64, &smem[1][1][0][0], tid);   // B_k0(1)
  stage_half(Ag, 64, &smem[1][0][0][0], tid);   // A_k0(1)
  stage_half(Bg, 96, &smem[1][1][1][0], tid);   // B_k1(1)
  // 14 loads outstanding; wait to 6 => tile0's 8 landed, 3 halves of tile1 in flight.
  asm volatile("s_waitcnt vmcnt(6)" ::: "memory");
  __builtin_amdgcn_sched_barrier(0);
  BAR();

  f16x8 af[4], bf[4];

  for (int t = 0; t < NT; ++t) {
    const int b = t & 1;
    const _Float16* Ak0 = &smem[b][0][0][0];
    const _Float16* Ak1 = &smem[b][0][1][0];
    const _Float16* Bk0 = &smem[b][1][0][0];
    const _Float16* Bk1 = &smem[b][1][1][0];
    const size_t kn1 = (size_t)(t + 1) * 64;
    const size_t kn2 = (size_t)(t + 2) * 64;

    // ---- P1: read A(mh0,k0)+B(k0); stage A_k1(t+1); MFMA mh0 x ks0
#pragma unroll
    for (int m = 0; m < 4; ++m) af[m] = frag(Ak0, wr * 128 + m * 16 + lr, hi);
#pragma unroll
    for (int n = 0; n < 4; ++n) bf[n] = frag(Bk0, wc * 64 + n * 16 + lr, hi);
    if (t + 1 < NT) stage_half(Ag, kn1 + 32, &smem[b ^ 1][0][1][0], tid);
    BAR();
    LGKM0();
    __builtin_amdgcn_s_setprio(1);
#pragma unroll
    for (int m = 0; m < 4; ++m)
#pragma unroll
      for (int n = 0; n < 4; ++n)
        acc[m][n] = __builtin_amdgcn_mfma_f32_16x16x32_f16(af[m], bf[n], acc[m][n], 0, 0, 0);
    __builtin_amdgcn_s_setprio(0);
    BAR();

    // ---- P2: read A(mh1,k0); stage B_k0(t+2); MFMA mh1 x ks0 (bf held)
#pragma unroll
    for (int m = 0; m < 4; ++m) af[m] = frag(Ak0, wr * 128 + 64 + m * 16 + lr, hi);
    if (t + 2 < NT) stage_half(Bg, kn2, &smem[b][1][0][0], tid);
    BAR();
    LGKM0();
    __builtin_amdgcn_s_setprio(1);
#pragma unroll
    for (int m = 0; m < 4; ++m)
#pragma unroll
      for (int n = 0; n < 4; ++n)
        acc[4 + m][n] = __builtin_amdgcn_mfma_f32_16x16x32_f16(af[m], bf[n], acc[4 + m][n], 0, 0, 0);
    __builtin_amdgcn_s_setprio(0);
    BAR();

    // ---- P3: read A(mh0,k1)+B(k1); stage A_k0(t+2); MFMA mh0 x ks1
#pragma unroll
    for (int m = 0; m < 4; ++m) af[m] = frag(Ak1, wr * 128 + m * 16 + lr, hi);
#pragma unroll
    for (int n = 0; n < 4; ++n) bf[n] = frag(Bk1, wc * 64 + n * 16 + lr, hi);
    if (t + 2 < NT) stage_half(Ag, kn2, &smem[b][0][0][0], tid);
    BAR();
    LGKM0();
    __builtin_amdgcn_s_setprio(1);
#pragma unroll
    for (int m = 0; m < 4; ++m)
#pragma unroll
      for (int n = 0; n < 4; ++n)
        acc[m][n] = __builtin_amdgcn_mfma_f32_16x16x32_f16(af[m], bf[n], acc[m][n], 0, 0, 0);
    __builtin_amdgcn_s_setprio(0);
    BAR();

    // ---- P4: read A(mh1,k1); stage B_k1(t+2); vmcnt(6); MFMA mh1 x ks1
#pragma unroll
    for (int m = 0; m < 4; ++m) af[m] = frag(Ak1, wr * 128 + 64 + m * 16 + lr, hi);
    if (t + 2 < NT) stage_half(Bg, kn2 + 32, &smem[b][1][1][0], tid);
    // steady state: 6 outstanding (t+1 leftovers) + 8 issued this tile = 14;
    // wait to 6 => ALL of tile t+1 landed, {B_k0,A_k0,B_k1}(t+2) in flight.
    if (t < NT - 2) asm volatile("s_waitcnt vmcnt(6)" ::: "memory");
    else            asm volatile("s_waitcnt vmcnt(0)" ::: "memory");
    __builtin_amdgcn_sched_barrier(0);
    BAR();
    LGKM0();
    __builtin_amdgcn_s_setprio(1);
#pragma unroll
    for (int m = 0; m < 4; ++m)
#pragma unroll
      for (int n = 0; n < 4; ++n)
        acc[4 + m][n] = __builtin_amdgcn_mfma_f32_16x16x32_f16(af[m], bf[n], acc[4 + m][n], 0, 0, 0);
    __builtin_amdgcn_s_setprio(0);
    BAR();
  }

  // ---- epilogue: y = acc*scale + bias. C/D map: col=lane&15, row=(lane>>4)*4+reg.
  const float s = scale_p[0];
  float bv[4];
#pragma unroll
  for (int n = 0; n < 4; ++n) bv[n] = bias[brow0 + wc * 64 + n * 16 + lr];
#pragma unroll
  for (int mi = 0; mi < 8; ++mi) {
    const int row0 = arow0 + wr * 128 + (mi >> 2) * 64 + (mi & 3) * 16 + hi * 4;
#pragma unroll
    for (int n = 0; n < 4; ++n) {
      const int col = brow0 + wc * 64 + n * 16 + lr;
      const f32x4 v = acc[mi][n];
#pragma unroll
      for (int j = 0; j < 4; ++j)
        out[(size_t)(row0 + j) * N_TOT + col] = v[j] * s + bv[n];
    }
  }
}

// ---------------- fallback (no workspace): r1 DIRECT 128^2 kernel ----------------

__global__ __launch_bounds__(256) void gemm_direct(
    const float* __restrict__ Xf, const int* __restrict__ Wq,
    const float* __restrict__ scale_p, const float* __restrict__ bias,
    float* __restrict__ out)
{
  __shared__ _Float16 ldsA[128 * 64];
  __shared__ _Float16 ldsB[128 * 64];
  const int tid = threadIdx.x, lane = tid & 63, wave = tid >> 6;
  const int wr = wave >> 1, wc = wave & 1;
  const int bid = blockIdx.x;
  const int wg  = (bid & 7) * 512 + (bid >> 3);
  const int arow0 = (wg & 31) * 128, brow0 = (wg >> 5) * 128;
  f32x4 acc[4][4];
#pragma unroll
  for (int m = 0; m < 4; ++m)
#pragma unroll
    for (int n = 0; n < 4; ++n) acc[m][n] = (f32x4){0.f, 0.f, 0.f, 0.f};
  const int srow = tid >> 3, schunk = tid & 7;
  const int lr = lane & 15, hi = lane >> 4;
  for (int kt = 0; kt < K_TOT / 64; ++kt) {
    const size_t kbase = (size_t)kt * 64;
    __syncthreads();
#pragma unroll
    for (int i = 0; i < 4; ++i) {
      const int row = i * 32 + srow;
      const int p = schunk ^ (row & 7);
      const float* gx = Xf + (size_t)(arow0 + row) * K_TOT + kbase + schunk * 8;
      const int*   gw = Wq + (size_t)(brow0 + row) * K_TOT + kbase + schunk * 8;
      float4 x0 = ((const float4*)gx)[0];
      float4 x1 = ((const float4*)gx)[1];
      int4   w0 = ((const int4*)gw)[0];
      int4   w1 = ((const int4*)gw)[1];
      f16x8 ha = { (_Float16)x0.x, (_Float16)x0.y, (_Float16)x0.z, (_Float16)x0.w,
                   (_Float16)x1.x, (_Float16)x1.y, (_Float16)x1.z, (_Float16)x1.w };
      f16x8 hb = { (_Float16)w0.x, (_Float16)w0.y, (_Float16)w0.z, (_Float16)w0.w,
                   (_Float16)w1.x, (_Float16)w1.y, (_Float16)w1.z, (_Float16)w1.w };
      *(f16x8*)(ldsA + row * 64 + p * 8) = ha;
      *(f16x8*)(ldsB + row * 64 + p * 8) = hb;
    }
    __syncthreads();
#pragma unroll
    for (int s2 = 0; s2 < 2; ++s2) {
      f16x8 af2[4], bf2[4];
#pragma unroll
      for (int m = 0; m < 4; ++m) {
        const int r = wr * 64 + m * 16 + lr;
        af2[m] = *(const f16x8*)(ldsA + r * 64 + (((s2 * 4 + hi) ^ (r & 7)) * 8));
      }
#pragma unroll
      for (int n = 0; n < 4; ++n) {
        const int r = wc * 64 + n * 16 + lr;
        bf2[n] = *(const f16x8*)(ldsB + r * 64 + (((s2 * 4 + hi) ^ (r & 7)) * 8));
      }
#pragma unroll
      for (int m = 0; m < 4; ++m)
#pragma unroll
        for (int n = 0; n < 4; ++n)
          acc[m][n] = __builtin_amdgcn_mfma_f32_16x16x32_f16(af2[m], bf2[n], acc[m][n], 0, 0, 0);
    }
  }
  const float s = scale_p[0];
#pragma unroll
  for (int n = 0; n < 4; ++n) {
    const int col = brow0 + wc * 64 + n * 16 + lr;
    const float bvv = bias[col];
#pragma unroll
    for (int m = 0; m < 4; ++m) {
      const int row0 = arow0 + wr * 64 + m * 16 + hi * 4;
      const f32x4 v = acc[m][n];
#pragma unroll
      for (int j = 0; j < 4; ++j)
        out[(size_t)(row0 + j) * N_TOT + col] = v[j] * s + bvv;
    }
  }
}

// ---------------- launch ----------------

extern "C" void kernel_launch(void* const* d_in, const int* in_sizes, int n_in,
                              void* d_out, int out_size, void* d_ws, size_t ws_size,
                              hipStream_t stream) {
  const float* x     = (const float*)d_in[0];
  const int*   wq    = (const int*)d_in[1];
  const float* scale = (const float*)d_in[2];
  const float* bias  = (const float*)d_in[3];
  float*       out   = (float*)d_out;

  const size_t nA = (size_t)M_TOT * K_TOT;
  const size_t nB = (size_t)N_TOT * K_TOT;
  const size_t need = (nA + nB) * sizeof(_Float16);  // 160 MiB

  if (ws_size >= need) {
    _Float16* A16 = (_Float16*)d_ws;
    _Float16* B16 = A16 + nA;
    cvt_x_f16<<<2048, 256, 0, stream>>>(x, A16, (int)(nA / 4));
    cvt_w_f16<<<2048, 256, 0, stream>>>(wq, B16, (int)(nB / 4));
    gemm8p<<<(M_TOT / 256) * (N_TOT / 256), 512, 0, stream>>>(A16, B16, scale, bias, out);
  } else {
    gemm_direct<<<(M_TOT / 128) * (N_TOT / 128), 256, 0, stream>>>(x, wq, scale, bias, out);
  }
}

// Round 3
// 664.631 us; speedup vs baseline: 1.5715x; 1.0212x over previous
//
#include <hip/hip_runtime.h>
#include <stdint.h>
#include <stddef.h>

// QuantizedColumnParallel: y[4096,16384] = x[4096,4096] @ (wq[16384,4096]*scale)^T + bias
// R3: fix LDS swizzle bit. Region rows = 32 f16 = 64B, bank space = 2 rows;
// conflict-free requires chunk XOR with (row>>1)&3 (not row&3). Both sides
// swizzled identically (rule #21): staged global source chunk + frag read chunk.

#define M_TOT 4096
#define N_TOT 16384
#define K_TOT 4096
#define NT    64          // K_TOT / 64
#define HALF  8192        // 256 rows * 32 cols (f16 elems) per K-half region

typedef __attribute__((ext_vector_type(8))) _Float16 f16x8;
typedef __attribute__((ext_vector_type(4))) _Float16 f16x4;
typedef __attribute__((ext_vector_type(4))) float    f32x4;

#define GLOAD_LDS16(g, l) __builtin_amdgcn_global_load_lds(                  \
    (const __attribute__((address_space(1))) void*)(g),                      \
    (__attribute__((address_space(3))) void*)(l), 16, 0, 0)

// ---------------- conversion pre-passes ----------------

__global__ __launch_bounds__(256) void cvt_x_f16(const float* __restrict__ x,
                                                 _Float16* __restrict__ o, int n4) {
  const int stride = gridDim.x * blockDim.x;
  for (int i = blockIdx.x * blockDim.x + threadIdx.x; i < n4; i += stride) {
    float4 v = ((const float4*)x)[i];
    f16x4 h = { (_Float16)v.x, (_Float16)v.y, (_Float16)v.z, (_Float16)v.w };
    ((f16x4*)o)[i] = h;
  }
}

__global__ __launch_bounds__(256) void cvt_w_f16(const int* __restrict__ w,
                                                 _Float16* __restrict__ o, int n4) {
  const int stride = gridDim.x * blockDim.x;
  for (int i = blockIdx.x * blockDim.x + threadIdx.x; i < n4; i += stride) {
    int4 v = ((const int4*)w)[i];
    f16x4 h = { (_Float16)v.x, (_Float16)v.y, (_Float16)v.z, (_Float16)v.w };
    ((f16x4*)o)[i] = h;
  }
}

// ---------------- 8-phase 256^2 GEMM ----------------

// Stage one K-half region (256 rows x 32 f16 = 16 KiB): 2 x global_load_lds(16B)
// per thread. LDS dest linear (uniform base + lane*16); XOR swizzle applied on
// the GLOBAL source chunk (rule #21).
__device__ __forceinline__ void stage_half(const _Float16* __restrict__ g,
                                           size_t kcol, _Float16* l, int tid) {
#pragma unroll
  for (int j = 0; j < 2; ++j) {
    const int ci  = j * 512 + tid;       // 0..1023 16B-chunks
    const int row = ci >> 2;             // 0..255
    const int sc  = (ci & 3) ^ ((row >> 1) & 3);   // R3: row bit 1, not bit 0
    GLOAD_LDS16(g + (size_t)row * K_TOT + kcol + sc * 8, l + ci * 8);
  }
}

// Swizzled fragment read: row r, K-chunk hi (0..3) within a 256x32 region.
// Within each 16-lane quarter, (r>>1)&3 sweeps all 4 values twice for even and
// odd rows alike => every 16B slot of the 128B bank space covered exactly 2x
// (2-way aliasing is free, m136).
__device__ __forceinline__ f16x8 frag(const _Float16* region, int r, int hi) {
  return *(const f16x8*)(region + r * 32 + (((hi ^ ((r >> 1) & 3))) * 8));
}

#define BAR()    __builtin_amdgcn_s_barrier()
#define LGKM0()  do { asm volatile("s_waitcnt lgkmcnt(0)" ::: "memory"); \
                      __builtin_amdgcn_sched_barrier(0); } while (0)

__global__ __launch_bounds__(512, 2) void gemm8p(
    const _Float16* __restrict__ A16, const _Float16* __restrict__ B16,
    const float* __restrict__ scale_p, const float* __restrict__ bias,
    float* __restrict__ out)
{
  // smem[buf][A=0|B=1][khalf][256*32]  = 128 KiB
  __shared__ _Float16 smem[2][2][2][HALF];

  const int tid  = threadIdx.x;
  const int lane = tid & 63;
  const int wave = tid >> 6;
  const int wr = wave >> 2;            // 0..1 (M)
  const int wc = wave & 3;             // 0..3 (N)
  const int lr = lane & 15;
  const int hi = lane >> 4;

  // XCD-aware swizzle: 1024 wg, 8 XCDs, 128 contiguous per XCD.
  const int bid = blockIdx.x;
  const int wg  = (bid & 7) * 128 + (bid >> 3);
  const int bm  = wg & 15;
  const int bn  = wg >> 4;
  const int arow0 = bm * 256;
  const int brow0 = bn * 256;

  const _Float16* Ag = A16 + (size_t)arow0 * K_TOT;
  const _Float16* Bg = B16 + (size_t)brow0 * K_TOT;

  f32x4 acc[8][4];
#pragma unroll
  for (int m = 0; m < 8; ++m)
#pragma unroll
    for (int n = 0; n < 4; ++n)
      acc[m][n] = (f32x4){0.f, 0.f, 0.f, 0.f};

  // ---- prologue: tile0 fully + {B_k0,A_k0,B_k1} of tile1 (issue order matters!)
  stage_half(Bg, 0,  &smem[0][1][0][0], tid);   // B_k0(0)
  stage_half(Ag, 0,  &smem[0][0][0][0], tid);   // A_k0(0)
  stage_half(Bg, 32, &smem[0][1][1][0], tid);   // B_k1(0)
  stage_half(Ag, 32, &smem[0][0][1][0], tid);   // A_k1(0)
  stage_half(Bg, 64, &smem[1][1][0][0], tid);   // B_k0(1)
  stage_half(Ag, 64, &smem[1][0][0][0], tid);   // A_k0(1)
  stage_half(Bg, 96, &smem[1][1][1][0], tid);   // B_k1(1)
  // 14 loads outstanding; wait to 6 => tile0's 8 landed, 3 halves of tile1 in flight.
  asm volatile("s_waitcnt vmcnt(6)" ::: "memory");
  __builtin_amdgcn_sched_barrier(0);
  BAR();

  f16x8 af[4], bf[4];

  for (int t = 0; t < NT; ++t) {
    const int b = t & 1;
    const _Float16* Ak0 = &smem[b][0][0][0];
    const _Float16* Ak1 = &smem[b][0][1][0];
    const _Float16* Bk0 = &smem[b][1][0][0];
    const _Float16* Bk1 = &smem[b][1][1][0];
    const size_t kn1 = (size_t)(t + 1) * 64;
    const size_t kn2 = (size_t)(t + 2) * 64;

    // ---- P1: read A(mh0,k0)+B(k0); stage A_k1(t+1); MFMA mh0 x ks0
#pragma unroll
    for (int m = 0; m < 4; ++m) af[m] = frag(Ak0, wr * 128 + m * 16 + lr, hi);
#pragma unroll
    for (int n = 0; n < 4; ++n) bf[n] = frag(Bk0, wc * 64 + n * 16 + lr, hi);
    if (t + 1 < NT) stage_half(Ag, kn1 + 32, &smem[b ^ 1][0][1][0], tid);
    BAR();
    LGKM0();
    __builtin_amdgcn_s_setprio(1);
#pragma unroll
    for (int m = 0; m < 4; ++m)
#pragma unroll
      for (int n = 0; n < 4; ++n)
        acc[m][n] = __builtin_amdgcn_mfma_f32_16x16x32_f16(af[m], bf[n], acc[m][n], 0, 0, 0);
    __builtin_amdgcn_s_setprio(0);
    BAR();

    // ---- P2: read A(mh1,k0); stage B_k0(t+2); MFMA mh1 x ks0 (bf held)
#pragma unroll
    for (int m = 0; m < 4; ++m) af[m] = frag(Ak0, wr * 128 + 64 + m * 16 + lr, hi);
    if (t + 2 < NT) stage_half(Bg, kn2, &smem[b][1][0][0], tid);
    BAR();
    LGKM0();
    __builtin_amdgcn_s_setprio(1);
#pragma unroll
    for (int m = 0; m < 4; ++m)
#pragma unroll
      for (int n = 0; n < 4; ++n)
        acc[4 + m][n] = __builtin_amdgcn_mfma_f32_16x16x32_f16(af[m], bf[n], acc[4 + m][n], 0, 0, 0);
    __builtin_amdgcn_s_setprio(0);
    BAR();

    // ---- P3: read A(mh0,k1)+B(k1); stage A_k0(t+2); MFMA mh0 x ks1
#pragma unroll
    for (int m = 0; m < 4; ++m) af[m] = frag(Ak1, wr * 128 + m * 16 + lr, hi);
#pragma unroll
    for (int n = 0; n < 4; ++n) bf[n] = frag(Bk1, wc * 64 + n * 16 + lr, hi);
    if (t + 2 < NT) stage_half(Ag, kn2, &smem[b][0][0][0], tid);
    BAR();
    LGKM0();
    __builtin_amdgcn_s_setprio(1);
#pragma unroll
    for (int m = 0; m < 4; ++m)
#pragma unroll
      for (int n = 0; n < 4; ++n)
        acc[m][n] = __builtin_amdgcn_mfma_f32_16x16x32_f16(af[m], bf[n], acc[m][n], 0, 0, 0);
    __builtin_amdgcn_s_setprio(0);
    BAR();

    // ---- P4: read A(mh1,k1); stage B_k1(t+2); vmcnt(6); MFMA mh1 x ks1
#pragma unroll
    for (int m = 0; m < 4; ++m) af[m] = frag(Ak1, wr * 128 + 64 + m * 16 + lr, hi);
    if (t + 2 < NT) stage_half(Bg, kn2 + 32, &smem[b][1][1][0], tid);
    // steady state: 6 outstanding (t+1 leftovers) + 8 issued this tile = 14;
    // wait to 6 => ALL of tile t+1 landed, {B_k0,A_k0,B_k1}(t+2) in flight.
    if (t < NT - 2) asm volatile("s_waitcnt vmcnt(6)" ::: "memory");
    else            asm volatile("s_waitcnt vmcnt(0)" ::: "memory");
    __builtin_amdgcn_sched_barrier(0);
    BAR();
    LGKM0();
    __builtin_amdgcn_s_setprio(1);
#pragma unroll
    for (int m = 0; m < 4; ++m)
#pragma unroll
      for (int n = 0; n < 4; ++n)
        acc[4 + m][n] = __builtin_amdgcn_mfma_f32_16x16x32_f16(af[m], bf[n], acc[4 + m][n], 0, 0, 0);
    __builtin_amdgcn_s_setprio(0);
    BAR();
  }

  // ---- epilogue: y = acc*scale + bias. C/D map: col=lane&15, row=(lane>>4)*4+reg.
  const float s = scale_p[0];
  float bv[4];
#pragma unroll
  for (int n = 0; n < 4; ++n) bv[n] = bias[brow0 + wc * 64 + n * 16 + lr];
#pragma unroll
  for (int mi = 0; mi < 8; ++mi) {
    const int row0 = arow0 + wr * 128 + (mi >> 2) * 64 + (mi & 3) * 16 + hi * 4;
#pragma unroll
    for (int n = 0; n < 4; ++n) {
      const int col = brow0 + wc * 64 + n * 16 + lr;
      const f32x4 v = acc[mi][n];
#pragma unroll
      for (int j = 0; j < 4; ++j)
        out[(size_t)(row0 + j) * N_TOT + col] = v[j] * s + bv[n];
    }
  }
}

// ---------------- fallback (no workspace): DIRECT 128^2 kernel ----------------

__global__ __launch_bounds__(256) void gemm_direct(
    const float* __restrict__ Xf, const int* __restrict__ Wq,
    const float* __restrict__ scale_p, const float* __restrict__ bias,
    float* __restrict__ out)
{
  __shared__ _Float16 ldsA[128 * 64];
  __shared__ _Float16 ldsB[128 * 64];
  const int tid = threadIdx.x, lane = tid & 63, wave = tid >> 6;
  const int wr = wave >> 1, wc = wave & 1;
  const int bid = blockIdx.x;
  const int wg  = (bid & 7) * 512 + (bid >> 3);
  const int arow0 = (wg & 31) * 128, brow0 = (wg >> 5) * 128;
  f32x4 acc[4][4];
#pragma unroll
  for (int m = 0; m < 4; ++m)
#pragma unroll
    for (int n = 0; n < 4; ++n) acc[m][n] = (f32x4){0.f, 0.f, 0.f, 0.f};
  const int srow = tid >> 3, schunk = tid & 7;
  const int lr = lane & 15, hi = lane >> 4;
  for (int kt = 0; kt < K_TOT / 64; ++kt) {
    const size_t kbase = (size_t)kt * 64;
    __syncthreads();
#pragma unroll
    for (int i = 0; i < 4; ++i) {
      const int row = i * 32 + srow;
      const int p = schunk ^ (row & 7);
      const float* gx = Xf + (size_t)(arow0 + row) * K_TOT + kbase + schunk * 8;
      const int*   gw = Wq + (size_t)(brow0 + row) * K_TOT + kbase + schunk * 8;
      float4 x0 = ((const float4*)gx)[0];
      float4 x1 = ((const float4*)gx)[1];
      int4   w0 = ((const int4*)gw)[0];
      int4   w1 = ((const int4*)gw)[1];
      f16x8 ha = { (_Float16)x0.x, (_Float16)x0.y, (_Float16)x0.z, (_Float16)x0.w,
                   (_Float16)x1.x, (_Float16)x1.y, (_Float16)x1.z, (_Float16)x1.w };
      f16x8 hb = { (_Float16)w0.x, (_Float16)w0.y, (_Float16)w0.z, (_Float16)w0.w,
                   (_Float16)w1.x, (_Float16)w1.y, (_Float16)w1.z, (_Float16)w1.w };
      *(f16x8*)(ldsA + row * 64 + p * 8) = ha;
      *(f16x8*)(ldsB + row * 64 + p * 8) = hb;
    }
    __syncthreads();
#pragma unroll
    for (int s2 = 0; s2 < 2; ++s2) {
      f16x8 af2[4], bf2[4];
#pragma unroll
      for (int m = 0; m < 4; ++m) {
        const int r = wr * 64 + m * 16 + lr;
        af2[m] = *(const f16x8*)(ldsA + r * 64 + (((s2 * 4 + hi) ^ (r & 7)) * 8));
      }
#pragma unroll
      for (int n = 0; n < 4; ++n) {
        const int r = wc * 64 + n * 16 + lr;
        bf2[n] = *(const f16x8*)(ldsB + r * 64 + (((s2 * 4 + hi) ^ (r & 7)) * 8));
      }
#pragma unroll
      for (int m = 0; m < 4; ++m)
#pragma unroll
        for (int n = 0; n < 4; ++n)
          acc[m][n] = __builtin_amdgcn_mfma_f32_16x16x32_f16(af2[m], bf2[n], acc[m][n], 0, 0, 0);
    }
  }
  const float s = scale_p[0];
#pragma unroll
  for (int n = 0; n < 4; ++n) {
    const int col = brow0 + wc * 64 + n * 16 + lr;
    const float bvv = bias[col];
#pragma unroll
    for (int m = 0; m < 4; ++m) {
      const int row0 = arow0 + wr * 64 + m * 16 + hi * 4;
      const f32x4 v = acc[m][n];
#pragma unroll
      for (int j = 0; j < 4; ++j)
        out[(size_t)(row0 + j) * N_TOT + col] = v[j] * s + bvv;
    }
  }
}

// ---------------- launch ----------------

extern "C" void kernel_launch(void* const* d_in, const int* in_sizes, int n_in,
                              void* d_out, int out_size, void* d_ws, size_t ws_size,
                              hipStream_t stream) {
  const float* x     = (const float*)d_in[0];
  const int*   wq    = (const int*)d_in[1];
  const float* scale = (const float*)d_in[2];
  const float* bias  = (const float*)d_in[3];
  float*       out   = (float*)d_out;

  const size_t nA = (size_t)M_TOT * K_TOT;
  const size_t nB = (size_t)N_TOT * K_TOT;
  const size_t need = (nA + nB) * sizeof(_Float16);  // 160 MiB

  if (ws_size >= need) {
    _Float16* A16 = (_Float16*)d_ws;
    _Float16* B16 = A16 + nA;
    cvt_x_f16<<<2048, 256, 0, stream>>>(x, A16, (int)(nA / 4));
    cvt_w_f16<<<2048, 256, 0, stream>>>(wq, B16, (int)(nB / 4));
    gemm8p<<<(M_TOT / 256) * (N_TOT / 256), 512, 0, stream>>>(A16, B16, scale, bias, out);
  } else {
    gemm_direct<<<(M_TOT / 128) * (N_TOT / 128), 256, 0, stream>>>(x, wq, scale, bias, out);
  }
}

// Round 4
// 421.214 us; speedup vs baseline: 2.4797x; 1.5779x over previous
//
#include <hip/hip_runtime.h>
#include <stdint.h>
#include <stddef.h>

// QuantizedColumnParallel: y[4096,16384] = x[4096,4096] @ (wq[16384,4096]*scale)^T + bias
// R4: int8 path. w is EXACTLY int8; x quantized per-row (sx=rowmax/127).
// mfma_i32_16x16x64_i8 (2x f16 OP rate), exact int32 accumulate,
// y = acc*(sx[row]*scale)+bias. 256^2 tile, BK=64, TRIPLE-buffered LDS (96KB),
// 2 phases/K-tile, counted vmcnt(4), proven-conflict-free chunk swizzle.

#define M_TOT 4096
#define N_TOT 16384
#define K_TOT 4096
#define NT    64          // K-tiles

typedef __attribute__((ext_vector_type(4))) int      v4i;
typedef __attribute__((ext_vector_type(8))) _Float16 f16x8;
typedef __attribute__((ext_vector_type(4))) float    f32x4;

#define GLOAD_LDS16(g, l) __builtin_amdgcn_global_load_lds(                  \
    (const __attribute__((address_space(1))) void*)(g),                      \
    (__attribute__((address_space(3))) void*)(l), 16, 0, 0)

// ---------------- conversion pre-passes ----------------

// x: one block per row (4096 f32). Row max -> sx, quantize to int8.
__global__ __launch_bounds__(256) void cvt_x_i8(const float* __restrict__ x,
                                                signed char* __restrict__ o,
                                                float* __restrict__ sx) {
  const int row = blockIdx.x;
  const int tid = threadIdx.x;
  const float* xr = x + (size_t)row * K_TOT;
  float4 v[4];
  float mx = 0.f;
#pragma unroll
  for (int j = 0; j < 4; ++j) {
    v[j] = ((const float4*)xr)[tid * 4 + j];
    mx = fmaxf(mx, fmaxf(fmaxf(fabsf(v[j].x), fabsf(v[j].y)),
                         fmaxf(fabsf(v[j].z), fabsf(v[j].w))));
  }
#pragma unroll
  for (int off = 32; off; off >>= 1) mx = fmaxf(mx, __shfl_xor(mx, off));
  __shared__ float wm[4];
  if ((tid & 63) == 0) wm[tid >> 6] = mx;
  __syncthreads();
  const float m4 = fmaxf(fmaxf(wm[0], wm[1]), fmaxf(wm[2], wm[3]));
  const float smax = fmaxf(m4, 1e-6f);
  const float inv  = 127.0f / smax;
  if (tid == 0) sx[row] = smax / 127.0f;
  int p[4];
#pragma unroll
  for (int j = 0; j < 4; ++j) {
    int q0 = (int)rintf(v[j].x * inv), q1 = (int)rintf(v[j].y * inv);
    int q2 = (int)rintf(v[j].z * inv), q3 = (int)rintf(v[j].w * inv);
    q0 = max(-127, min(127, q0)); q1 = max(-127, min(127, q1));
    q2 = max(-127, min(127, q2)); q3 = max(-127, min(127, q3));
    p[j] = (q0 & 255) | ((q1 & 255) << 8) | ((q2 & 255) << 16) | (q3 << 24);
  }
  ((int4*)(o + (size_t)row * K_TOT))[tid] = make_int4(p[0], p[1], p[2], p[3]);
}

// w: int32 (-127..127) -> int8, 16 elems/thread.
__global__ __launch_bounds__(256) void cvt_w_i8(const int* __restrict__ w,
                                                signed char* __restrict__ o, int n16) {
  const int stride = gridDim.x * blockDim.x;
  for (int i = blockIdx.x * blockDim.x + threadIdx.x; i < n16; i += stride) {
    int p[4];
#pragma unroll
    for (int j = 0; j < 4; ++j) {
      int4 a = ((const int4*)w)[i * 4 + j];
      p[j] = (a.x & 255) | ((a.y & 255) << 8) | ((a.z & 255) << 16) | (a.w << 24);
    }
    ((int4*)o)[i] = make_int4(p[0], p[1], p[2], p[3]);
  }
}

// ---------------- i8 GEMM: 256^2 tile, 2 phases/K-tile, triple-buffered ----------------

// Stage one 256x64-byte region (16 KiB): 2 x global_load_lds(16B)/thread.
// LDS dest linear; XOR swizzle on GLOBAL source chunk (rule #21). Byte geometry
// identical to R3's verified conflict-free layout (64B rows, 4 chunks).
__device__ __forceinline__ void stage_i8(const signed char* __restrict__ g,
                                         size_t kbyte, signed char* l, int tid) {
#pragma unroll
  for (int j = 0; j < 2; ++j) {
    const int ci  = j * 512 + tid;       // 0..1023 16B-chunks
    const int row = ci >> 2;             // 0..255
    const int sc  = (ci & 3) ^ ((row >> 1) & 3);
    GLOAD_LDS16(g + (size_t)row * K_TOT + kbyte + sc * 16, l + ci * 16);
  }
}

// Swizzled fragment read: row r, 16B chunk hi (0..3). 2-way aliasing = free.
__device__ __forceinline__ v4i fragi(const signed char* region, int r, int hi) {
  return *(const v4i*)(region + r * 64 + ((hi ^ ((r >> 1) & 3)) << 4));
}

#define BAR()    __builtin_amdgcn_s_barrier()
#define LGKM0()  do { asm volatile("s_waitcnt lgkmcnt(0)" ::: "memory"); \
                      __builtin_amdgcn_sched_barrier(0); } while (0)

__global__ __launch_bounds__(512, 2) void gemm_i8(
    const signed char* __restrict__ A8, const signed char* __restrict__ B8,
    const float* __restrict__ sx, const float* __restrict__ scale_p,
    const float* __restrict__ bias, float* __restrict__ out)
{
  // lds[buf(3)][A=0|B=1][256*64 bytes] = 96 KiB
  __shared__ __align__(16) signed char lds[3][2][16384];

  const int tid  = threadIdx.x;
  const int lane = tid & 63;
  const int wave = tid >> 6;
  const int wr = wave >> 2;            // 0..1 (M)
  const int wc = wave & 3;             // 0..3 (N)
  const int lr = lane & 15;
  const int hi = lane >> 4;

  // XCD-aware swizzle: 1024 wg, 8 XCDs, 128 contiguous per XCD; bm fast.
  const int bid = blockIdx.x;
  const int wg  = (bid & 7) * 128 + (bid >> 3);
  const int bm  = wg & 15;
  const int bn  = wg >> 4;
  const int arow0 = bm * 256;
  const int brow0 = bn * 256;

  const signed char* Ag = A8 + (size_t)arow0 * K_TOT;
  const signed char* Bg = B8 + (size_t)brow0 * K_TOT;

  v4i acc[8][4];
#pragma unroll
  for (int m = 0; m < 8; ++m)
#pragma unroll
    for (int n = 0; n < 4; ++n)
      acc[m][n] = (v4i){0, 0, 0, 0};

  // ---- prologue: A(0),B(0),A(1),B(1); wait tile0, keep tile1 in flight.
  stage_i8(Ag, 0,  &lds[0][0][0], tid);
  stage_i8(Bg, 0,  &lds[0][1][0], tid);
  stage_i8(Ag, 64, &lds[1][0][0], tid);
  stage_i8(Bg, 64, &lds[1][1][0], tid);
  asm volatile("s_waitcnt vmcnt(4)" ::: "memory");
  __builtin_amdgcn_sched_barrier(0);
  BAR();

  v4i af[4], bf[4];

  for (int t = 0; t < NT; ++t) {
    const signed char* At = &lds[t % 3][0][0];
    const signed char* Bt = &lds[t % 3][1][0];
    signed char* L2a = &lds[(t + 2) % 3][0][0];
    signed char* L2b = &lds[(t + 2) % 3][1][0];
    const size_t k2 = (size_t)(t + 2) * 64;

    // ---- P1: read af0-3 + bf0-3; stage A(t+2); MFMA acc[0..3][*]
#pragma unroll
    for (int m = 0; m < 4; ++m) af[m] = fragi(At, wr * 128 + m * 16 + lr, hi);
#pragma unroll
    for (int n = 0; n < 4; ++n) bf[n] = fragi(Bt, wc * 64 + n * 16 + lr, hi);
    if (t + 2 < NT) stage_i8(Ag, k2, L2a, tid);
    BAR();
    LGKM0();
    __builtin_amdgcn_s_setprio(1);
#pragma unroll
    for (int m = 0; m < 4; ++m)
#pragma unroll
      for (int n = 0; n < 4; ++n)
        acc[m][n] = __builtin_amdgcn_mfma_i32_16x16x64_i8(af[m], bf[n], acc[m][n], 0, 0, 0);
    __builtin_amdgcn_s_setprio(0);
    BAR();

    // ---- P2: read af4-7 (bf held); stage B(t+2); vmcnt(4); MFMA acc[4..7][*]
#pragma unroll
    for (int m = 0; m < 4; ++m) af[m] = fragi(At, wr * 128 + 64 + m * 16 + lr, hi);
    if (t + 2 < NT) stage_i8(Bg, k2, L2b, tid);
    // steady: outstanding = {A(t+1),B(t+1),A(t+2),B(t+2)} = 8 loads; keep 4 youngest.
    if (t < NT - 2) asm volatile("s_waitcnt vmcnt(4)" ::: "memory");
    else            asm volatile("s_waitcnt vmcnt(0)" ::: "memory");
    __builtin_amdgcn_sched_barrier(0);
    BAR();
    LGKM0();
    __builtin_amdgcn_s_setprio(1);
#pragma unroll
    for (int m = 0; m < 4; ++m)
#pragma unroll
      for (int n = 0; n < 4; ++n)
        acc[4 + m][n] = __builtin_amdgcn_mfma_i32_16x16x64_i8(af[m], bf[n], acc[4 + m][n], 0, 0, 0);
    __builtin_amdgcn_s_setprio(0);
    BAR();
  }

  // ---- epilogue: y = acc * (sx[row]*scale) + bias.
  // C/D map (dtype-independent): col=lane&15, row=(lane>>4)*4+reg.
  const float s = scale_p[0];
  float bv[4];
#pragma unroll
  for (int n = 0; n < 4; ++n) bv[n] = bias[brow0 + wc * 64 + n * 16 + lr];
#pragma unroll
  for (int mi = 0; mi < 8; ++mi) {
    const int row0 = arow0 + wr * 128 + (mi >> 2) * 64 + (mi & 3) * 16 + hi * 4;
    float sc4[4];
#pragma unroll
    for (int j = 0; j < 4; ++j) sc4[j] = sx[row0 + j] * s;
#pragma unroll
    for (int n = 0; n < 4; ++n) {
      const int col = brow0 + wc * 64 + n * 16 + lr;
      const v4i v = acc[mi][n];
#pragma unroll
      for (int j = 0; j < 4; ++j)
        out[(size_t)(row0 + j) * N_TOT + col] = (float)v[j] * sc4[j] + bv[n];
    }
  }
}

// ---------------- fallback (no workspace): f16 DIRECT 128^2 kernel ----------------

typedef __attribute__((ext_vector_type(8))) _Float16 f16x8_t;

__global__ __launch_bounds__(256) void gemm_direct(
    const float* __restrict__ Xf, const int* __restrict__ Wq,
    const float* __restrict__ scale_p, const float* __restrict__ bias,
    float* __restrict__ out)
{
  __shared__ _Float16 ldsA[128 * 64];
  __shared__ _Float16 ldsB[128 * 64];
  const int tid = threadIdx.x, lane = tid & 63, wave = tid >> 6;
  const int wr = wave >> 1, wc = wave & 1;
  const int bid = blockIdx.x;
  const int wg  = (bid & 7) * 512 + (bid >> 3);
  const int arow0 = (wg & 31) * 128, brow0 = (wg >> 5) * 128;
  f32x4 acc[4][4];
#pragma unroll
  for (int m = 0; m < 4; ++m)
#pragma unroll
    for (int n = 0; n < 4; ++n) acc[m][n] = (f32x4){0.f, 0.f, 0.f, 0.f};
  const int srow = tid >> 3, schunk = tid & 7;
  const int lr = lane & 15, hi = lane >> 4;
  for (int kt = 0; kt < K_TOT / 64; ++kt) {
    const size_t kbase = (size_t)kt * 64;
    __syncthreads();
#pragma unroll
    for (int i = 0; i < 4; ++i) {
      const int row = i * 32 + srow;
      const int p = schunk ^ (row & 7);
      const float* gx = Xf + (size_t)(arow0 + row) * K_TOT + kbase + schunk * 8;
      const int*   gw = Wq + (size_t)(brow0 + row) * K_TOT + kbase + schunk * 8;
      float4 x0 = ((const float4*)gx)[0];
      float4 x1 = ((const float4*)gx)[1];
      int4   w0 = ((const int4*)gw)[0];
      int4   w1 = ((const int4*)gw)[1];
      f16x8 ha = { (_Float16)x0.x, (_Float16)x0.y, (_Float16)x0.z, (_Float16)x0.w,
                   (_Float16)x1.x, (_Float16)x1.y, (_Float16)x1.z, (_Float16)x1.w };
      f16x8 hb = { (_Float16)w0.x, (_Float16)w0.y, (_Float16)w0.z, (_Float16)w0.w,
                   (_Float16)w1.x, (_Float16)w1.y, (_Float16)w1.z, (_Float16)w1.w };
      *(f16x8*)(ldsA + row * 64 + p * 8) = ha;
      *(f16x8*)(ldsB + row * 64 + p * 8) = hb;
    }
    __syncthreads();
#pragma unroll
    for (int s2 = 0; s2 < 2; ++s2) {
      f16x8 af2[4], bf2[4];
#pragma unroll
      for (int m = 0; m < 4; ++m) {
        const int r = wr * 64 + m * 16 + lr;
        af2[m] = *(const f16x8*)(ldsA + r * 64 + (((s2 * 4 + hi) ^ (r & 7)) * 8));
      }
#pragma unroll
      for (int n = 0; n < 4; ++n) {
        const int r = wc * 64 + n * 16 + lr;
        bf2[n] = *(const f16x8*)(ldsB + r * 64 + (((s2 * 4 + hi) ^ (r & 7)) * 8));
      }
#pragma unroll
      for (int m = 0; m < 4; ++m)
#pragma unroll
        for (int n = 0; n < 4; ++n)
          acc[m][n] = __builtin_amdgcn_mfma_f32_16x16x32_f16(af2[m], bf2[n], acc[m][n], 0, 0, 0);
    }
  }
  const float s = scale_p[0];
#pragma unroll
  for (int n = 0; n < 4; ++n) {
    const int col = brow0 + wc * 64 + n * 16 + lr;
    const float bvv = bias[col];
#pragma unroll
    for (int m = 0; m < 4; ++m) {
      const int row0 = arow0 + wr * 64 + m * 16 + hi * 4;
      const f32x4 v = acc[m][n];
#pragma unroll
      for (int j = 0; j < 4; ++j)
        out[(size_t)(row0 + j) * N_TOT + col] = v[j] * s + bvv;
    }
  }
}

// ---------------- launch ----------------

extern "C" void kernel_launch(void* const* d_in, const int* in_sizes, int n_in,
                              void* d_out, int out_size, void* d_ws, size_t ws_size,
                              hipStream_t stream) {
  const float* x     = (const float*)d_in[0];
  const int*   wq    = (const int*)d_in[1];
  const float* scale = (const float*)d_in[2];
  const float* bias  = (const float*)d_in[3];
  float*       out   = (float*)d_out;

  const size_t nA = (size_t)M_TOT * K_TOT;   // 16.7M
  const size_t nB = (size_t)N_TOT * K_TOT;   // 67.1M
  const size_t need = nA + nB + M_TOT * sizeof(float);  // ~84 MiB

  if (ws_size >= need) {
    signed char* A8 = (signed char*)d_ws;
    signed char* B8 = A8 + nA;
    float*       sx = (float*)(B8 + nB);
    cvt_x_i8<<<M_TOT, 256, 0, stream>>>(x, A8, sx);
    cvt_w_i8<<<2048, 256, 0, stream>>>(wq, B8, (int)(nB / 16));
    gemm_i8<<<(M_TOT / 256) * (N_TOT / 256), 512, 0, stream>>>(A8, B8, sx, scale, bias, out);
  } else {
    gemm_direct<<<(M_TOT / 128) * (N_TOT / 128), 256, 0, stream>>>(x, wq, scale, bias, out);
  }
}